// Round 10
// baseline (372.971 us; speedup 1.0000x reference)
//
#include <hip/hip_runtime.h>
#include <hip/hip_bf16.h>

// N=50000 nodes, E=800000 edges, D=96 (in = hidden = out)
#define NNODES 50000
#define NEDGES 800000
#define DIM    96
#define NBUCK  196      // ceil(N/256): bucket = dst >> 8
#define CAP    4608     // per-bucket col capacity (mean 4096, sigma 64 -> +8 sigma)
#define TM     64       // rows per GEMM block
#define XPAD   104      // LDS row stride (bf16), 16B-aligned
#define PCH    3125     // edges per partition chunk (256 * 3125 = 800000)
#define NCHK   256      // number of chunks
#define HP     256      // hist/hoff row stride (ints)

typedef __attribute__((ext_vector_type(8))) short   short8;   // 8 bf16 = 4 VGPRs
typedef __attribute__((ext_vector_type(4))) float   float4v;  // MFMA acc

// flags[0] = 1 if float tensors are bf16, 0 if f32
// flags[1] = 1 if edge_index is int64, 0 if int32
__device__ __forceinline__ float loadF(const void* p, long i, int isbf) {
    return isbf ? __bfloat162float(((const __hip_bfloat16*)p)[i])
                : ((const float*)p)[i];
}
__device__ __forceinline__ int clampN(int v) {
    return v < 0 ? 0 : (v >= NNODES ? NNODES - 1 : v);
}

// single wave: device-side dtype sniff (in_sizes are ELEMENT COUNTS host-side
// and cannot disambiguate dtype -- bit patterns can).
__global__ void k_sniff(const unsigned* __restrict__ xw,
                        const unsigned* __restrict__ ew,
                        int* __restrict__ flags) {
    int lane = threadIdx.x;
    int bad = 0, nz = 0;
    for (int r = 0; r < 4; ++r) {
        unsigned w  = xw[lane + 64 * r];
        unsigned lo = w & 0xffffu;
        unsigned ex = (lo >> 7) & 0xffu;
        if (!(lo == 0u || (ex >= 90u && ex <= 145u))) bad++;
        unsigned o = ew[2 * (lane + 64 * r) + 1];
        if (o != 0u) nz++;
    }
    for (int off = 32; off; off >>= 1) {
        bad += __shfl_down(bad, off);
        nz  += __shfl_down(nz,  off);
    }
    if (lane == 0) {
        flags[0] = (bad <= 32) ? 1 : 0;
        flags[1] = (nz  <  4) ? 1 : 0;
    }
}

// deterministic bucket-grouping partition: each block decodes its 3125-edge
// chunk, groups it by dst-bucket ENTIRELY IN LDS (histogram + scan + local
// scatter), writes the grouped chunk back contiguously (coalesced) plus the
// per-chunk (count, offset) tables. No global atomics, no grid sync.
__global__ __launch_bounds__(256) void k_part(const int* __restrict__ w,
                                              const int* __restrict__ flags,
                                              int* __restrict__ hist,
                                              int* __restrict__ hoff,
                                              unsigned* __restrict__ ebuf) {
    __shared__ unsigned pack[PCH];    // 12.5 KB raw decode
    __shared__ unsigned opack[PCH];   // 12.5 KB bucket-grouped
    __shared__ int h[256];
    __shared__ int sc[256];
    const int is64 = flags[1];
    const int tid = threadIdx.x;
    const int blk = blockIdx.x;
    const int e0  = blk * PCH;

    h[tid] = 0;
    __syncthreads();
    if (is64) {
        const long long* wl = (const long long*)w;
        for (int k = tid; k < PCH; k += 256) {
            int s = clampN((int)wl[e0 + k]);
            int d = clampN((int)wl[NEDGES + e0 + k]);
            pack[k] = ((unsigned)d << 16) | (unsigned)s;
            atomicAdd(&h[d >> 8], 1);
        }
    } else {
        for (int k = tid; k < PCH; k += 256) {
            int s = clampN(w[e0 + k]);
            int d = clampN(w[NEDGES + e0 + k]);
            pack[k] = ((unsigned)d << 16) | (unsigned)s;
            atomicAdd(&h[d >> 8], 1);
        }
    }
    __syncthreads();
    int v = h[tid];
    sc[tid] = v;
    __syncthreads();
    for (int off = 1; off < 256; off <<= 1) {
        int t2 = (tid >= off) ? sc[tid - off] : 0;
        __syncthreads();
        sc[tid] += t2;
        __syncthreads();
    }
    const int excl = sc[tid] - v;          // in-chunk exclusive bucket offset
    hist[blk * HP + tid] = v;
    hoff[blk * HP + tid] = excl;
    h[tid] = excl;                         // reuse as local cursor
    __syncthreads();
    for (int k = tid; k < PCH; k += 256) {
        unsigned r = pack[k];
        int pos = atomicAdd(&h[(r >> 16) >> 8], 1);   // LDS atomic
        opack[pos] = r;
    }
    __syncthreads();
    for (int k = tid; k < PCH; k += 256)   // coalesced writeback
        ebuf[e0 + k] = opack[k];
}

// per-bucket local CSR (512 threads, 196 blocks): thread-pairs walk the 256
// per-chunk slices of this bucket; histogram 256 local dsts, scan ->
// rowbeg/rowend/dinv in PADDED col coordinates, LDS-cursor scatter (u16).
__global__ __launch_bounds__(512) void k_csr(const unsigned* __restrict__ ebuf,
                                             const int* __restrict__ hist,
                                             const int* __restrict__ hoff,
                                             int* __restrict__ rowbeg,
                                             int* __restrict__ rowend,
                                             unsigned short* __restrict__ col,
                                             float* __restrict__ dinv) {
    __shared__ int h256[256];
    __shared__ int sc[256];
    __shared__ int cur[256];
    __shared__ int scnt[256];
    __shared__ int soff[256];
    const int b   = blockIdx.x;
    const int tid = threadIdx.x;

    if (tid < 256) {
        scnt[tid] = hist[tid * HP + b];
        soff[tid] = hoff[tid * HP + b];
        h256[tid] = 0;
    }
    __syncthreads();
    const int ch  = tid >> 1;          // chunk 0..255
    const int par = tid & 1;
    {
        const int cnt = scnt[ch];
        const int off = ch * PCH + soff[ch];
        for (int j = par; j < cnt; j += 2)
            atomicAdd(&h256[(ebuf[off + j] >> 16) & 255], 1);
    }
    __syncthreads();
    int v = 0;
    if (tid < 256) { v = h256[tid]; sc[tid] = v; }
    __syncthreads();
    for (int off = 1; off < 256; off <<= 1) {
        int t2 = 0;
        if (tid < 256 && tid >= off) t2 = sc[tid - off];
        __syncthreads();
        if (tid < 256) sc[tid] += t2;
        __syncthreads();
    }
    if (tid < 256) {
        int start = b * CAP + sc[tid] - v;   // exclusive, padded coordinates
        cur[tid] = start;
        int node = b * 256 + tid;
        if (node < NNODES) {
            rowbeg[node] = start;
            rowend[node] = start + v;
            dinv[node] = rsqrtf((float)v + 1.0f);   // +1 self loop
        }
    }
    __syncthreads();
    {
        const int cnt = scnt[ch];
        const int off = ch * PCH + soff[ch];
        const int lim = (b + 1) * CAP;
        for (int j = par; j < cnt; j += 2) {
            unsigned r = ebuf[off + j];
            int pos = atomicAdd(&cur[(r >> 16) & 255], 1);
            if (pos < lim) col[pos] = (unsigned short)(r & 0xffffu);
        }
    }
}

// MFMA GEMM: g[row,:] = bf16( dinv[row] * (X[row,:] @ W) )
// block = 256 (4 waves), 64 rows/block; X strip + W^T staged in LDS as bf16.
__global__ __launch_bounds__(256) void k_gemm_mfma(
        const void* __restrict__ X, int x_force_bf16,
        const void* __restrict__ W,
        const float* __restrict__ dinv,
        __hip_bfloat16* __restrict__ g,
        const int* __restrict__ flags) {
    __shared__ __hip_bfloat16 Xs[TM * XPAD];
    __shared__ __hip_bfloat16 Wt[DIM * XPAD];

    const int t    = threadIdx.x;
    const int fbf  = flags[0];
    const int xbf  = x_force_bf16 ? 1 : fbf;
    const int row0 = blockIdx.x * TM;

    // stage W^T (vectorized when f32)
    if (!fbf) {
        const float4* Wv = (const float4*)W;
        for (int idx = t; idx < DIM * DIM / 4; idx += 256) {
            int k = idx / (DIM / 4);
            int n = (idx - k * (DIM / 4)) * 4;
            float4 w4 = Wv[idx];
            Wt[(n + 0) * XPAD + k] = __float2bfloat16(w4.x);
            Wt[(n + 1) * XPAD + k] = __float2bfloat16(w4.y);
            Wt[(n + 2) * XPAD + k] = __float2bfloat16(w4.z);
            Wt[(n + 3) * XPAD + k] = __float2bfloat16(w4.w);
        }
    } else {
        for (int idx = t; idx < DIM * DIM; idx += 256) {
            int k = idx / DIM, n = idx - k * DIM;
            Wt[n * XPAD + k] = __float2bfloat16(loadF(W, idx, 1));
        }
    }
    // stage X strip (vectorized both paths)
    if (!xbf) {
        const float4* Xv = (const float4*)X;
        for (int idx = t; idx < TM * (DIM / 4); idx += 256) {
            int r = idx / (DIM / 4);
            int c = (idx - r * (DIM / 4)) * 4;
            int gr = row0 + r;
            float4 vv = {0.f, 0.f, 0.f, 0.f};
            if (gr < NNODES) vv = Xv[(size_t)gr * (DIM / 4) + (c >> 2)];
            *(__hip_bfloat162*)&Xs[r * XPAD + c] =
                __halves2bfloat162(__float2bfloat16(vv.x), __float2bfloat16(vv.y));
            *(__hip_bfloat162*)&Xs[r * XPAD + c + 2] =
                __halves2bfloat162(__float2bfloat16(vv.z), __float2bfloat16(vv.w));
        }
    } else {
        const short* Xs16 = (const short*)X;
        for (int idx = t; idx < TM * (DIM / 8); idx += 256) {
            int r  = idx / (DIM / 8);
            int c8 = idx - r * (DIM / 8);
            int gr = row0 + r;
            short8 vv = {0, 0, 0, 0, 0, 0, 0, 0};
            if (gr < NNODES) vv = *(const short8*)(Xs16 + (size_t)gr * DIM + c8 * 8);
            *(short8*)((short*)Xs + r * XPAD + c8 * 8) = vv;
        }
    }
    __syncthreads();

    const int wave = t >> 6;
    const int lane = t & 63;
    const int m    = lane & 15;
    const int quad = lane >> 4;

    const short* xsp = (const short*)Xs;
    short8 a[3];
#pragma unroll
    for (int kt = 0; kt < 3; ++kt)
        a[kt] = *(const short8*)(xsp + (wave * 16 + m) * XPAD + kt * 32 + quad * 8);

    float dv[4];
#pragma unroll
    for (int r2 = 0; r2 < 4; ++r2) {
        int gr = row0 + wave * 16 + quad * 4 + r2;
        dv[r2] = (gr < NNODES) ? dinv[gr] : 0.f;
    }

    const short* wtp = (const short*)Wt;
#pragma unroll
    for (int nt = 0; nt < 6; ++nt) {
        float4v acc = {0.f, 0.f, 0.f, 0.f};
#pragma unroll
        for (int kt = 0; kt < 3; ++kt) {
            short8 b = *(const short8*)(wtp + (nt * 16 + m) * XPAD + kt * 32 + quad * 8);
            acc = __builtin_amdgcn_mfma_f32_16x16x32_bf16(a[kt], b, acc, 0, 0, 0);
        }
#pragma unroll
        for (int r2 = 0; r2 < 4; ++r2) {
            int gr = row0 + wave * 16 + quad * 4 + r2;
            if (gr < NNODES)
                g[(size_t)gr * DIM + nt * 16 + m] = __float2bfloat16(acc[r2] * dv[r2]);
        }
    }
}

// XCD-sliced aggregate: slice = blockIdx&7 handles feature cols
// [slice*12, slice*12+12). With round-robin block->XCD dispatch, slice s is
// pinned to XCD s, so each XCD's L2 working set = its 1.2 MB column slice of
// g + col (1.6 MB) + rowptrs (0.4 MB) = 3.2 MB < 4 MB L2 -> gathers become
// L2 hits instead of the 8-XCD-replicated 67 MB HBM fetch.
// Wave layout: lane = p*8 + n (p = col-pair 0..5 within slice, n = neighbor
// 0..7) -> 8 neighbors per gather instruction; reduce over n via shfl_xor.
// Per 16-neighbor volley: 2 col loads + 2 gathers (same instr count/row as
// the row-major scheme; the win is pure L2 locality).
__global__ __launch_bounds__(256) void k_aggr(
        const __hip_bfloat16* __restrict__ g,
        const int* __restrict__ rowbeg,
        const int* __restrict__ rowend,
        const unsigned short* __restrict__ col,
        const float* __restrict__ dinv,
        const void* __restrict__ b,
        const void* __restrict__ a1,
        void* __restrict__ out,
        const int* __restrict__ flags, int prelu) {
    const int wave  = threadIdx.x >> 6;
    const int lane  = threadIdx.x & 63;
    const int slice = blockIdx.x & 7;
    const int rblk  = blockIdx.x >> 3;
    const int p     = lane >> 3;                 // 0..7 (0..5 active)
    const int n     = lane & 7;                  // neighbor sub-index
    const bool act  = p < 6;
    const int cp    = slice * 6 + (act ? p : 5); // col-pair index 0..47
    const int fbf   = flags[0];
    const __hip_bfloat162* gv = (const __hip_bfloat162*)g;

    const float bx = loadF(b, 2 * cp,     fbf);
    const float by = loadF(b, 2 * cp + 1, fbf);
    const float alpha = prelu ? loadF(a1, 0, fbf) : 0.f;

    for (int r = 0; r < 8; ++r) {
        const int row = rblk * 32 + wave * 8 + r;
        if (row >= NNODES) return;               // rows increase with r
        float2 acc = {0.f, 0.f};
        {
            float2 s2 = __bfloat1622float2(gv[(size_t)row * 48 + cp]);
            if (n == 0) acc = s2;                // self loop counted once
        }
        const int p0 = rowbeg[row], p1 = rowend[row];
        int i = p0;
        for (; i + 16 <= p1; i += 16) {          // full 16-neighbor volleys
            int s0 = col[i + n];
            int s1 = col[i + 8 + n];
            float2 v0 = __bfloat1622float2(gv[(size_t)s0 * 48 + cp]);
            float2 v1 = __bfloat1622float2(gv[(size_t)s1 * 48 + cp]);
            acc.x += v0.x + v1.x;
            acc.y += v0.y + v1.y;
        }
        if (i < p1) {                            // predicated 16-wide tail
            const int last = p1 - 1;
            int i0 = i + n,     j0 = i0 > last ? last : i0;
            int i1 = i + 8 + n, j1 = i1 > last ? last : i1;
            int s0 = col[j0];
            int s1 = col[j1];
            float2 v0 = __bfloat1622float2(gv[(size_t)s0 * 48 + cp]);
            float2 v1 = __bfloat1622float2(gv[(size_t)s1 * 48 + cp]);
            if (i0 < p1) { acc.x += v0.x; acc.y += v0.y; }
            if (i1 < p1) { acc.x += v1.x; acc.y += v1.y; }
        }
#pragma unroll
        for (int off = 1; off < 8; off <<= 1) {  // reduce over n (stays in p-group)
            acc.x += __shfl_xor(acc.x, off);
            acc.y += __shfl_xor(acc.y, off);
        }
        if (n == 0 && act) {
            float dv = dinv[row];
            float vx = dv * acc.x + bx;
            float vy = dv * acc.y + by;
            if (prelu) {
                vx = vx > 0.f ? vx : alpha * vx;
                vy = vy > 0.f ? vy : alpha * vy;
            }
            if (prelu || fbf) {
                ((__hip_bfloat162*)out)[(size_t)row * 48 + cp] =
                    __halves2bfloat162(__float2bfloat16(vx), __float2bfloat16(vy));
            } else {
                float2 o; o.x = vx; o.y = vy;
                ((float2*)out)[(size_t)row * 48 + cp] = o;
            }
        }
    }
}

extern "C" void kernel_launch(void* const* d_in, const int* in_sizes, int n_in,
                              void* d_out, int out_size, void* d_ws, size_t ws_size,
                              hipStream_t stream) {
    const void* x  = d_in[0];
    const int*  ei = (const int*)d_in[1];
    const void* W1 = d_in[2];
    const void* b1 = d_in[3];
    const void* a1 = d_in[4];
    const void* W2 = d_in[5];
    const void* b2 = d_in[6];

    size_t off = 0;
    auto alloc = [&](size_t bytes) { size_t p = off; off = (off + bytes + 255) & ~(size_t)255; return p; };
    char* ws = (char*)d_ws;
    int*            flags  = (int*)           (ws + alloc(1024));
    float*          dinv   = (float*)         (ws + alloc((size_t)NNODES * 4));
    int*            rowbeg = (int*)           (ws + alloc((size_t)NNODES * 4));
    int*            rowend = (int*)           (ws + alloc((size_t)NNODES * 4));
    int*            hist   = (int*)           (ws + alloc((size_t)NCHK * HP * 4));
    int*            hoff   = (int*)           (ws + alloc((size_t)NCHK * HP * 4));
    unsigned*       ebuf   = (unsigned*)      (ws + alloc((size_t)NEDGES * 4));
    unsigned short* col    = (unsigned short*)(ws + alloc((size_t)NBUCK * CAP * 2 + 256));
    __hip_bfloat16* g      = (__hip_bfloat16*)(ws + alloc((size_t)NNODES * DIM * 2));
    __hip_bfloat16* g2     = (__hip_bfloat16*)(ws + alloc((size_t)NNODES * DIM * 2));
    if (ws_size < off) return;   // ~27 MiB

    // ---- CSR build: device sniff + deterministic LDS-grouped counting sort
    k_sniff<<<1, 64, 0, stream>>>((const unsigned*)x, (const unsigned*)ei, flags);
    k_part <<<NCHK, 256, 0, stream>>>(ei, flags, hist, hoff, ebuf);
    k_csr  <<<NBUCK, 512, 0, stream>>>(ebuf, hist, hoff, rowbeg, rowend, col, dinv);

    const int gemm_grid = (NNODES + TM - 1) / TM;            // 782
    const int aggr_grid = ((NNODES + 31) / 32) * 8;          // 1563*8 = 12504

    // ---- layer 1 ----
    k_gemm_mfma<<<gemm_grid, 256, 0, stream>>>(x, 0, W1, dinv, g, flags);
    k_aggr<<<aggr_grid, 256, 0, stream>>>(g, rowbeg, rowend, col, dinv, b1, a1, g2, flags, 1);

    // ---- layer 2 ----
    k_gemm_mfma<<<gemm_grid, 256, 0, stream>>>(g2, 1, W2, dinv, g, flags);
    k_aggr<<<aggr_grid, 256, 0, stream>>>(g, rowbeg, rowend, col, dinv, b2, a1, d_out, flags, 0);
}

// Round 11
// 190.227 us; speedup vs baseline: 1.9607x; 1.9607x over previous
//
#include <hip/hip_runtime.h>
#include <hip/hip_bf16.h>

// N=50000 nodes, E=800000 edges, D=96 (in = hidden = out)
#define NNODES 50000
#define NEDGES 800000
#define DIM    96
#define NBUCK  196      // ceil(N/256): bucket = dst >> 8
#define CAP    4608     // per-bucket col capacity (mean 4096, sigma 64 -> +8 sigma)
#define TM     64       // rows per GEMM block
#define XPAD   104      // LDS row stride (bf16), 16B-aligned
#define PCH    3125     // edges per partition chunk (256 * 3125 = 800000)
#define NCHK   256      // number of chunks
#define HP     256      // hist/hoff row stride (ints)

typedef __attribute__((ext_vector_type(8))) short   short8;   // 8 bf16 = 4 VGPRs
typedef __attribute__((ext_vector_type(4))) float   float4v;  // MFMA acc

// flags[0] = 1 if float tensors are bf16, 0 if f32
// flags[1] = 1 if edge_index is int64, 0 if int32
__device__ __forceinline__ float loadF(const void* p, long i, int isbf) {
    return isbf ? __bfloat162float(((const __hip_bfloat16*)p)[i])
                : ((const float*)p)[i];
}
__device__ __forceinline__ int clampN(int v) {
    return v < 0 ? 0 : (v >= NNODES ? NNODES - 1 : v);
}

// deterministic bucket-grouping partition WITH inline dtype sniff.
// Each block sniffs its own copy of the first 256 words of x / edge pairs
// (deterministic -> same answer in every block; block 0 publishes flags for
// the downstream kernels). Then: decode own 3125-edge chunk, group by
// dst-bucket entirely in LDS (histogram + scan + local scatter), write the
// grouped chunk back coalesced + per-chunk (count,offset) tables.
// No global atomics, no grid sync, no separate sniff dispatch.
__global__ __launch_bounds__(256) void k_part(const unsigned* __restrict__ xw,
                                              const int* __restrict__ w,
                                              int* __restrict__ flags,
                                              int* __restrict__ hist,
                                              int* __restrict__ hoff,
                                              unsigned* __restrict__ ebuf) {
    __shared__ unsigned pack[PCH];    // 12.5 KB raw decode
    __shared__ unsigned opack[PCH];   // 12.5 KB bucket-grouped
    __shared__ int h[256];
    __shared__ int sc[256];
    __shared__ int sn[2];
    const int tid = threadIdx.x;
    const int blk = blockIdx.x;
    const int e0  = blk * PCH;

    // ---- local sniff (every block; no cross-block dependency) ------------
    if (tid < 2) sn[tid] = 0;
    h[tid] = 0;
    __syncthreads();
    {
        unsigned wv = xw[tid];
        unsigned lo = wv & 0xffffu;
        unsigned ex = (lo >> 7) & 0xffu;
        if (!(lo == 0u || (ex >= 90u && ex <= 145u))) atomicAdd(&sn[0], 1);
        if (((const unsigned*)w)[2 * tid + 1] != 0u)   atomicAdd(&sn[1], 1);
    }
    __syncthreads();
    const int is64 = (sn[1] < 4) ? 1 : 0;
    if (blk == 0 && tid == 0) {
        flags[0] = (sn[0] <= 32) ? 1 : 0;
        flags[1] = is64;
    }

    // ---- decode + LDS bucket-grouping + coalesced writeback --------------
    if (is64) {
        const long long* wl = (const long long*)w;
        for (int k = tid; k < PCH; k += 256) {
            int s = clampN((int)wl[e0 + k]);
            int d = clampN((int)wl[NEDGES + e0 + k]);
            pack[k] = ((unsigned)d << 16) | (unsigned)s;
            atomicAdd(&h[d >> 8], 1);
        }
    } else {
        for (int k = tid; k < PCH; k += 256) {
            int s = clampN(w[e0 + k]);
            int d = clampN(w[NEDGES + e0 + k]);
            pack[k] = ((unsigned)d << 16) | (unsigned)s;
            atomicAdd(&h[d >> 8], 1);
        }
    }
    __syncthreads();
    int v = h[tid];
    sc[tid] = v;
    __syncthreads();
    for (int off = 1; off < 256; off <<= 1) {
        int t2 = (tid >= off) ? sc[tid - off] : 0;
        __syncthreads();
        sc[tid] += t2;
        __syncthreads();
    }
    const int excl = sc[tid] - v;          // in-chunk exclusive bucket offset
    hist[blk * HP + tid] = v;
    hoff[blk * HP + tid] = excl;
    h[tid] = excl;                         // reuse as local cursor
    __syncthreads();
    for (int k = tid; k < PCH; k += 256) {
        unsigned r = pack[k];
        int pos = atomicAdd(&h[(r >> 16) >> 8], 1);   // LDS atomic
        opack[pos] = r;
    }
    __syncthreads();
    for (int k = tid; k < PCH; k += 256)   // coalesced writeback
        ebuf[e0 + k] = opack[k];
}

// per-bucket local CSR (512 threads, 196 blocks): thread-pairs walk the 256
// per-chunk slices of this bucket; histogram 256 local dsts, scan ->
// rowbeg/rowend/dinv in PADDED col coordinates, LDS-cursor scatter (u16).
__global__ __launch_bounds__(512) void k_csr(const unsigned* __restrict__ ebuf,
                                             const int* __restrict__ hist,
                                             const int* __restrict__ hoff,
                                             int* __restrict__ rowbeg,
                                             int* __restrict__ rowend,
                                             unsigned short* __restrict__ col,
                                             float* __restrict__ dinv) {
    __shared__ int h256[256];
    __shared__ int sc[256];
    __shared__ int cur[256];
    __shared__ int scnt[256];
    __shared__ int soff[256];
    const int b   = blockIdx.x;
    const int tid = threadIdx.x;

    if (tid < 256) {
        scnt[tid] = hist[tid * HP + b];
        soff[tid] = hoff[tid * HP + b];
        h256[tid] = 0;
    }
    __syncthreads();
    const int ch  = tid >> 1;          // chunk 0..255
    const int par = tid & 1;
    {
        const int cnt = scnt[ch];
        const int off = ch * PCH + soff[ch];
        for (int j = par; j < cnt; j += 2)
            atomicAdd(&h256[(ebuf[off + j] >> 16) & 255], 1);
    }
    __syncthreads();
    int v = 0;
    if (tid < 256) { v = h256[tid]; sc[tid] = v; }
    __syncthreads();
    for (int off = 1; off < 256; off <<= 1) {
        int t2 = 0;
        if (tid < 256 && tid >= off) t2 = sc[tid - off];
        __syncthreads();
        if (tid < 256) sc[tid] += t2;
        __syncthreads();
    }
    if (tid < 256) {
        int start = b * CAP + sc[tid] - v;   // exclusive, padded coordinates
        cur[tid] = start;
        int node = b * 256 + tid;
        if (node < NNODES) {
            rowbeg[node] = start;
            rowend[node] = start + v;
            dinv[node] = rsqrtf((float)v + 1.0f);   // +1 self loop
        }
    }
    __syncthreads();
    {
        const int cnt = scnt[ch];
        const int off = ch * PCH + soff[ch];
        const int lim = (b + 1) * CAP;
        for (int j = par; j < cnt; j += 2) {
            unsigned r = ebuf[off + j];
            int pos = atomicAdd(&cur[(r >> 16) & 255], 1);
            if (pos < lim) col[pos] = (unsigned short)(r & 0xffffu);
        }
    }
}

// MFMA GEMM: g[row,:] = bf16( dinv[row] * (X[row,:] @ W) )
// block = 256 (4 waves), 64 rows/block; X strip + W^T staged in LDS as bf16.
__global__ __launch_bounds__(256) void k_gemm_mfma(
        const void* __restrict__ X, int x_force_bf16,
        const void* __restrict__ W,
        const float* __restrict__ dinv,
        __hip_bfloat16* __restrict__ g,
        const int* __restrict__ flags) {
    __shared__ __hip_bfloat16 Xs[TM * XPAD];
    __shared__ __hip_bfloat16 Wt[DIM * XPAD];

    const int t    = threadIdx.x;
    const int fbf  = flags[0];
    const int xbf  = x_force_bf16 ? 1 : fbf;
    const int row0 = blockIdx.x * TM;

    // stage W^T (vectorized when f32)
    if (!fbf) {
        const float4* Wv = (const float4*)W;
        for (int idx = t; idx < DIM * DIM / 4; idx += 256) {
            int k = idx / (DIM / 4);
            int n = (idx - k * (DIM / 4)) * 4;
            float4 w4 = Wv[idx];
            Wt[(n + 0) * XPAD + k] = __float2bfloat16(w4.x);
            Wt[(n + 1) * XPAD + k] = __float2bfloat16(w4.y);
            Wt[(n + 2) * XPAD + k] = __float2bfloat16(w4.z);
            Wt[(n + 3) * XPAD + k] = __float2bfloat16(w4.w);
        }
    } else {
        for (int idx = t; idx < DIM * DIM; idx += 256) {
            int k = idx / DIM, n = idx - k * DIM;
            Wt[n * XPAD + k] = __float2bfloat16(loadF(W, idx, 1));
        }
    }
    // stage X strip (vectorized both paths)
    if (!xbf) {
        const float4* Xv = (const float4*)X;
        for (int idx = t; idx < TM * (DIM / 4); idx += 256) {
            int r = idx / (DIM / 4);
            int c = (idx - r * (DIM / 4)) * 4;
            int gr = row0 + r;
            float4 vv = {0.f, 0.f, 0.f, 0.f};
            if (gr < NNODES) vv = Xv[(size_t)gr * (DIM / 4) + (c >> 2)];
            *(__hip_bfloat162*)&Xs[r * XPAD + c] =
                __halves2bfloat162(__float2bfloat16(vv.x), __float2bfloat16(vv.y));
            *(__hip_bfloat162*)&Xs[r * XPAD + c + 2] =
                __halves2bfloat162(__float2bfloat16(vv.z), __float2bfloat16(vv.w));
        }
    } else {
        const short* Xs16 = (const short*)X;
        for (int idx = t; idx < TM * (DIM / 8); idx += 256) {
            int r  = idx / (DIM / 8);
            int c8 = idx - r * (DIM / 8);
            int gr = row0 + r;
            short8 vv = {0, 0, 0, 0, 0, 0, 0, 0};
            if (gr < NNODES) vv = *(const short8*)(Xs16 + (size_t)gr * DIM + c8 * 8);
            *(short8*)((short*)Xs + r * XPAD + c8 * 8) = vv;
        }
    }
    __syncthreads();

    const int wave = t >> 6;
    const int lane = t & 63;
    const int m    = lane & 15;
    const int quad = lane >> 4;

    const short* xsp = (const short*)Xs;
    short8 a[3];
#pragma unroll
    for (int kt = 0; kt < 3; ++kt)
        a[kt] = *(const short8*)(xsp + (wave * 16 + m) * XPAD + kt * 32 + quad * 8);

    float dv[4];
#pragma unroll
    for (int r2 = 0; r2 < 4; ++r2) {
        int gr = row0 + wave * 16 + quad * 4 + r2;
        dv[r2] = (gr < NNODES) ? dinv[gr] : 0.f;
    }

    const short* wtp = (const short*)Wt;
#pragma unroll
    for (int nt = 0; nt < 6; ++nt) {
        float4v acc = {0.f, 0.f, 0.f, 0.f};
#pragma unroll
        for (int kt = 0; kt < 3; ++kt) {
            short8 b = *(const short8*)(wtp + (nt * 16 + m) * XPAD + kt * 32 + quad * 8);
            acc = __builtin_amdgcn_mfma_f32_16x16x32_bf16(a[kt], b, acc, 0, 0, 0);
        }
#pragma unroll
        for (int r2 = 0; r2 < 4; ++r2) {
            int gr = row0 + wave * 16 + quad * 4 + r2;
            if (gr < NNODES)
                g[(size_t)gr * DIM + nt * 16 + m] = __float2bfloat16(acc[r2] * dv[r2]);
        }
    }
}

// aggregate + epilogue: ONE WAVE per destination row, lanes 0..47 hold
// bfloat162 column pairs (one gather instruction = one 192B row, 100% of
// fetched sectors used -- measured optimal across 5 alternative schemes).
// Full 16-wide gather blocks + ONE predicated 16-wide tail block (clamped
// index -> duplicate loads are L1 hits, lanes beyond deg zeroed).
// Default regalloc (~24 VGPR) -> max occupancy; TLP hides miss latency.
__global__ __launch_bounds__(256) void k_aggr(
        const __hip_bfloat16* __restrict__ g,
        const int* __restrict__ rowbeg,
        const int* __restrict__ rowend,
        const unsigned short* __restrict__ col,
        const float* __restrict__ dinv,
        const void* __restrict__ b,
        const void* __restrict__ a1,
        void* __restrict__ out,
        const int* __restrict__ flags, int prelu) {
    const int wave = threadIdx.x >> 6;
    const int lane = threadIdx.x & 63;
    const int row  = blockIdx.x * 4 + wave;
    if (row >= NNODES) return;                       // wave-uniform
    const int fbf = flags[0];
    const __hip_bfloat162* gv = (const __hip_bfloat162*)g;
    const int c = lane;                              // 0..47 active

    float2 acc = {0.f, 0.f};
    if (c < 48) acc = __bfloat1622float2(gv[(size_t)row * 48 + c]);  // self loop

    const int p0 = rowbeg[row], p1 = rowend[row];
    int i = p0;
    for (; i + 16 <= p1; i += 16) {                  // full blocks
        int s[16];
#pragma unroll
        for (int k = 0; k < 16; ++k) s[k] = col[i + k];
        if (c < 48) {
            float2 v[16];
#pragma unroll
            for (int k = 0; k < 16; ++k)
                v[k] = __bfloat1622float2(gv[(size_t)s[k] * 48 + c]);
            float2 t0, t1, t2, t3;
            t0.x = (v[0].x + v[1].x) + (v[2].x + v[3].x);
            t0.y = (v[0].y + v[1].y) + (v[2].y + v[3].y);
            t1.x = (v[4].x + v[5].x) + (v[6].x + v[7].x);
            t1.y = (v[4].y + v[5].y) + (v[6].y + v[7].y);
            t2.x = (v[8].x + v[9].x) + (v[10].x + v[11].x);
            t2.y = (v[8].y + v[9].y) + (v[10].y + v[11].y);
            t3.x = (v[12].x + v[13].x) + (v[14].x + v[15].x);
            t3.y = (v[12].y + v[13].y) + (v[14].y + v[15].y);
            acc.x += (t0.x + t1.x) + (t2.x + t3.x);
            acc.y += (t0.y + t1.y) + (t2.y + t3.y);
        }
    }
    if (i < p1) {                                    // predicated tail block
        const int last = p1 - 1;
        int s[16];
#pragma unroll
        for (int k = 0; k < 16; ++k) {
            int idx = i + k;
            s[k] = col[idx > last ? last : idx];
        }
        if (c < 48) {
            float2 v[16];
#pragma unroll
            for (int k = 0; k < 16; ++k) {
                v[k] = __bfloat1622float2(gv[(size_t)s[k] * 48 + c]);
                if (i + k > last) { v[k].x = 0.f; v[k].y = 0.f; }
            }
            float2 t0, t1, t2, t3;
            t0.x = (v[0].x + v[1].x) + (v[2].x + v[3].x);
            t0.y = (v[0].y + v[1].y) + (v[2].y + v[3].y);
            t1.x = (v[4].x + v[5].x) + (v[6].x + v[7].x);
            t1.y = (v[4].y + v[5].y) + (v[6].y + v[7].y);
            t2.x = (v[8].x + v[9].x) + (v[10].x + v[11].x);
            t2.y = (v[8].y + v[9].y) + (v[10].y + v[11].y);
            t3.x = (v[12].x + v[13].x) + (v[14].x + v[15].x);
            t3.y = (v[12].y + v[13].y) + (v[14].y + v[15].y);
            acc.x += (t0.x + t1.x) + (t2.x + t3.x);
            acc.y += (t0.y + t1.y) + (t2.y + t3.y);
        }
    }

    if (c < 48) {
        float dv = dinv[row];
        float vx = dv * acc.x + loadF(b, 2 * c,     fbf);
        float vy = dv * acc.y + loadF(b, 2 * c + 1, fbf);
        if (prelu) {
            float alpha = loadF(a1, 0, fbf);
            vx = vx > 0.f ? vx : alpha * vx;
            vy = vy > 0.f ? vy : alpha * vy;
            ((__hip_bfloat162*)out)[(size_t)row * 48 + c] =
                __halves2bfloat162(__float2bfloat16(vx), __float2bfloat16(vy));
        } else if (fbf) {
            ((__hip_bfloat162*)out)[(size_t)row * 48 + c] =
                __halves2bfloat162(__float2bfloat16(vx), __float2bfloat16(vy));
        } else {
            float2 o; o.x = vx; o.y = vy;
            ((float2*)out)[(size_t)row * 48 + c] = o;
        }
    }
}

extern "C" void kernel_launch(void* const* d_in, const int* in_sizes, int n_in,
                              void* d_out, int out_size, void* d_ws, size_t ws_size,
                              hipStream_t stream) {
    const void* x  = d_in[0];
    const int*  ei = (const int*)d_in[1];
    const void* W1 = d_in[2];
    const void* b1 = d_in[3];
    const void* a1 = d_in[4];
    const void* W2 = d_in[5];
    const void* b2 = d_in[6];

    size_t off = 0;
    auto alloc = [&](size_t bytes) { size_t p = off; off = (off + bytes + 255) & ~(size_t)255; return p; };
    char* ws = (char*)d_ws;
    int*            flags  = (int*)           (ws + alloc(1024));
    float*          dinv   = (float*)         (ws + alloc((size_t)NNODES * 4));
    int*            rowbeg = (int*)           (ws + alloc((size_t)NNODES * 4));
    int*            rowend = (int*)           (ws + alloc((size_t)NNODES * 4));
    int*            hist   = (int*)           (ws + alloc((size_t)NCHK * HP * 4));
    int*            hoff   = (int*)           (ws + alloc((size_t)NCHK * HP * 4));
    unsigned*       ebuf   = (unsigned*)      (ws + alloc((size_t)NEDGES * 4));
    unsigned short* col    = (unsigned short*)(ws + alloc((size_t)NBUCK * CAP * 2 + 256));
    __hip_bfloat16* g      = (__hip_bfloat16*)(ws + alloc((size_t)NNODES * DIM * 2));
    __hip_bfloat16* g2     = (__hip_bfloat16*)(ws + alloc((size_t)NNODES * DIM * 2));
    if (ws_size < off) return;   // ~27 MiB

    // ---- CSR build: 2 dispatches (sniff folded into k_part) --------------
    k_part<<<NCHK, 256, 0, stream>>>((const unsigned*)x, ei, flags, hist, hoff, ebuf);
    k_csr <<<NBUCK, 512, 0, stream>>>(ebuf, hist, hoff, rowbeg, rowend, col, dinv);

    const int gemm_grid = (NNODES + TM - 1) / TM;       // 782
    const int aggr_grid = (NNODES + 3) / 4;             // 12500 (4 rows/block)

    // ---- layer 1 ----
    k_gemm_mfma<<<gemm_grid, 256, 0, stream>>>(x, 0, W1, dinv, g, flags);
    k_aggr<<<aggr_grid, 256, 0, stream>>>(g, rowbeg, rowend, col, dinv, b1, a1, g2, flags, 1);

    // ---- layer 2 ----
    k_gemm_mfma<<<gemm_grid, 256, 0, stream>>>(g2, 1, W2, dinv, g, flags);
    k_aggr<<<aggr_grid, 256, 0, stream>>>(g, rowbeg, rowend, col, dinv, b2, a1, d_out, flags, 0);
}